// Round 7
// baseline (467.353 us; speedup 1.0000x reference)
//
#include <hip/hip_runtime.h>
#include <math.h>

typedef __attribute__((ext_vector_type(4))) float f32x4;
typedef __attribute__((ext_vector_type(8))) short bf16x8;

// Problem constants
#define NB 16
#define NT 2048
#define NMEL 80
#define NPOS 512          // stacked positions per batch
#define EDIM 16
#define NEMB 8192
#define ENCD 512
#define MROWS (NB*511)    // 8176 logit rows
#define MPAD 8192
#define NVT 32            // 8192 / 256 col tiles
#define NBLK 2048         // logits grid size

__device__ __forceinline__ unsigned short f2bf(float x) {
    union { float f; unsigned u; } v; v.f = x;
    unsigned r = v.u + 0x7fffu + ((v.u >> 16) & 1u);
    return (unsigned short)(r >> 16);
}

__device__ __forceinline__ void gl_lds16(const void* gsrc, void* lds) {
    __builtin_amdgcn_global_load_lds(
        (const __attribute__((address_space(1))) unsigned int*)gsrc,
        (__attribute__((address_space(3))) unsigned int*)lds,
        16, 0, 0);
}

// ---------------- Kernel 1: prep = codes (blocks 0..511) + enc->bf16 (512..1023)
//                  + tno->bf16 transpose (1024..2047). Also zeroes presence/sctrl.
__global__ __launch_bounds__(256) void prep_kernel(
    const float* __restrict__ feats, const float* __restrict__ proj,
    const float* __restrict__ emb, const float* __restrict__ enc,
    const float* __restrict__ tno,
    int* __restrict__ codes, int* __restrict__ presence, int* __restrict__ sctrl,
    unsigned short* __restrict__ encB, unsigned short* __restrict__ tnoT)
{
    __shared__ float embS[512][EDIM + 1];   // codes: col 16 = 0.5*||e||^2
    __shared__ float tileT[32][33];         // tno transpose staging
    const int bid = blockIdx.x;
    const int tid = threadIdx.x;

    if (bid < 512) {
        // ---- codes path ----
        const int lane = tid & 63;
        const int wave = tid >> 6;
        const int gbase = bid * 16 + wave * 4;
        if (bid < 32) presence[bid * 256 + tid] = 0;
        if (bid == 32 && tid < 64) sctrl[tid] = 0;

        float yn[4][EDIM];
        #pragma unroll
        for (int pi = 0; pi < 4; ++pi) {
            const int g = gbase + pi;
            const int b = g >> 9;
            const int i = g & 511;
            float xv[5];
            float s = 0.f, sq = 0.f;
            #pragma unroll
            for (int qq = 0; qq < 5; ++qq) {
                const int d = lane + 64 * qq;
                const int j = d / 80, k = d - j * 80;
                const float v = feats[((b * NT) + (i * 4 + j)) * NMEL + k];
                xv[qq] = v; s += v; sq += v * v;
            }
            for (int m = 1; m < 64; m <<= 1) { s += __shfl_xor(s, m); sq += __shfl_xor(sq, m); }
            const float mean = s * (1.0f / 320.0f);
            const float var  = sq * (1.0f / 320.0f) - mean * mean;
            const float rstd = rsqrtf(var + 1e-6f);
            float acc[EDIM];
            #pragma unroll
            for (int e = 0; e < EDIM; ++e) acc[e] = 0.f;
            #pragma unroll
            for (int qq = 0; qq < 5; ++qq) {
                const int d = lane + 64 * qq;
                const float xn = (xv[qq] - mean) * rstd;
                #pragma unroll
                for (int e = 0; e < EDIM; ++e) acc[e] += xn * proj[d * EDIM + e];
            }
            for (int m = 1; m < 64; m <<= 1) {
                #pragma unroll
                for (int e = 0; e < EDIM; ++e) acc[e] += __shfl_xor(acc[e], m);
            }
            float nsq = 0.f;
            #pragma unroll
            for (int e = 0; e < EDIM; ++e) nsq += acc[e] * acc[e];
            const float inv = 1.0f / (sqrtf(nsq) + 1e-8f);
            #pragma unroll
            for (int e = 0; e < EDIM; ++e) yn[pi][e] = acc[e] * inv;
        }

        float mind[4]; int mini[4];
        #pragma unroll
        for (int pi = 0; pi < 4; ++pi) { mind[pi] = INFINITY; mini[pi] = 0x7fffffff; }

        for (int c = 0; c < 16; ++c) {
            __syncthreads();
            #pragma unroll
            for (int r = 0; r < 32; ++r) {
                const int flat = r * 256 + tid;
                embS[flat >> 4][flat & 15] = emb[c * 8192 + flat];
            }
            __syncthreads();
            #pragma unroll
            for (int rr = 0; rr < 2; ++rr) {
                const int vl = tid * 2 + rr;
                float e2 = 0.f;
                #pragma unroll
                for (int e = 0; e < EDIM; ++e) e2 += embS[vl][e] * embS[vl][e];
                embS[vl][EDIM] = 0.5f * e2;
            }
            __syncthreads();
            #pragma unroll
            for (int qq = 0; qq < 8; ++qq) {
                const int vl = lane + 64 * qq;
                float ev[EDIM];
                #pragma unroll
                for (int e = 0; e < EDIM; ++e) ev[e] = embS[vl][e];
                const float h2 = embS[vl][EDIM];
                const int v = c * 512 + vl;
                #pragma unroll
                for (int pi = 0; pi < 4; ++pi) {
                    float dot = 0.f;
                    #pragma unroll
                    for (int e = 0; e < EDIM; ++e) dot += yn[pi][e] * ev[e];
                    const float sc = h2 - dot;
                    if (sc < mind[pi]) { mind[pi] = sc; mini[pi] = v; }
                }
            }
        }
        for (int m = 1; m < 64; m <<= 1) {
            #pragma unroll
            for (int pi = 0; pi < 4; ++pi) {
                const float ov = __shfl_xor(mind[pi], m);
                const int   oi = __shfl_xor(mini[pi], m);
                if (ov < mind[pi] || (ov == mind[pi] && oi < mini[pi])) { mind[pi] = ov; mini[pi] = oi; }
            }
        }
        if (lane == 0) {
            #pragma unroll
            for (int pi = 0; pi < 4; ++pi) codes[gbase + pi] = mini[pi];
        }
    } else if (bid < 1024) {
        // ---- enc f32 -> encB bf16 [8192][512], padded rows zero ----
        const int bid2 = bid - 512;          // 0..511 -> 16 rows each
        #pragma unroll
        for (int pass = 0; pass < 4; ++pass) {
            const int m = bid2 * 16 + pass * 4 + (tid >> 6);
            const int d = (tid & 63) * 8;
            bf16x8 o;
            if (m < MROWS) {
                const int b = m / 511, t = m - b * 511;
                const float4 f0 = *(const float4*)&enc[((size_t)(b * 512 + t)) * ENCD + d];
                const float4 f1 = *(const float4*)&enc[((size_t)(b * 512 + t)) * ENCD + d + 4];
                o[0] = f2bf(f0.x); o[1] = f2bf(f0.y); o[2] = f2bf(f0.z); o[3] = f2bf(f0.w);
                o[4] = f2bf(f1.x); o[5] = f2bf(f1.y); o[6] = f2bf(f1.z); o[7] = f2bf(f1.w);
            } else {
                o = (bf16x8){0,0,0,0,0,0,0,0};
            }
            *(bf16x8*)&encB[(size_t)m * ENCD + d] = o;
        }
    } else {
        // ---- tno f32 [512][8192] -> tnoT bf16 [8192][512] ----
        const int bid2 = bid - 1024;         // 0..1023 -> 4 tiles each
        const int tx = tid & 31, ty = tid >> 5;   // 32 x 8
        #pragma unroll
        for (int it = 0; it < 4; ++it) {
            const int tile = bid2 * 4 + it;       // 0..4095
            const int n0 = (tile & 255) * 32;
            const int k0 = (tile >> 8) * 32;
            __syncthreads();
            #pragma unroll
            for (int i = 0; i < 4; ++i)
                tileT[ty + 8 * i][tx] = tno[(size_t)(k0 + ty + 8 * i) * NEMB + n0 + tx];
            __syncthreads();
            #pragma unroll
            for (int i = 0; i < 4; ++i)
                tnoT[(size_t)(n0 + ty + 8 * i) * ENCD + k0 + tx] = f2bf(tileT[tx][ty + 8 * i]);
        }
    }
}

// ---------------- Kernel 2: bf16 MFMA GEMM 128x256 tile, 8 waves, BK=32, 3-buffer
//                  counted vmcnt(3) + fused softmax partials + last-block finalize ----
__global__ __launch_bounds__(512, 4) void logits_mfma(
    const unsigned short* __restrict__ encB, const unsigned short* __restrict__ tnoT,
    const int* __restrict__ codes, const int* __restrict__ lens,
    float* __restrict__ pm, float* __restrict__ ps, int* __restrict__ pidx,
    float* __restrict__ tgtlog, int* __restrict__ presence, int* __restrict__ sctrl,
    float* __restrict__ out)
{
    __shared__ __align__(16) unsigned short As3[3][128 * 32];   // 24 KB
    __shared__ __align__(16) unsigned short Bs3[3][256 * 32];   // 48 KB
    __shared__ int isLast;

    const int tid  = threadIdx.x;
    const int lane = tid & 63;
    const int wave = tid >> 6;           // 0..7
    const int wrM = wave >> 2;           // 0..1 -> 64-row band
    const int wcN = wave & 3;            // 0..3 -> 64-col band
    const int l15 = lane & 15, q = lane >> 4;

    // XCD mapping: each XCD owns 8 mt rows; vt sweeps within.
    const int bid = blockIdx.x;          // 0..2047
    const int xcd = bid & 7;
    const int idx = bid >> 3;            // 0..255
    const int mt  = xcd * 8 + (idx & 7); // 0..63
    const int vt  = idx >> 3;            // 0..31
    const int m0 = mt * 128, n0 = vt * 256;

    // staging: per gl_lds = 16 rows x 32 bf16 (64B rows, 4 chunks of 16B);
    // involution: LDS[r][slot] = global chunk slot ^ ((r>>1)&3)  (2-way free on read)
    const int r16 = lane >> 2;                               // 0..15
    const int gc8 = ((lane & 3) ^ ((lane >> 3) & 3)) * 8;    // pre-swizzled source chunk
    const size_t abase  = (size_t)(m0 + wave * 16 + r16) * ENCD + gc8;
    const size_t bbase0 = (size_t)(n0 + wave * 32 + r16) * ENCD + gc8;
    const size_t bbase1 = (size_t)(n0 + wave * 32 + 16 + r16) * ENCD + gc8;

#define STAGE(t, buf)                                                              \
    {                                                                              \
        const int k0s = (t) * 32;                                                  \
        gl_lds16(encB + abase  + k0s, &As3[buf][(wave * 16) * 32]);                \
        gl_lds16(tnoT + bbase0 + k0s, &Bs3[buf][(wave * 32) * 32]);                \
        gl_lds16(tnoT + bbase1 + k0s, &Bs3[buf][(wave * 32 + 16) * 32]);           \
    }

    f32x4 acc[4][4];
    #pragma unroll
    for (int i = 0; i < 4; ++i)
        #pragma unroll
        for (int j = 0; j < 4; ++j)
            acc[i][j] = (f32x4){0.f, 0.f, 0.f, 0.f};

    const int ca = (q ^ ((l15 >> 1) & 3)) * 8;   // swizzled read chunk (elements)

    STAGE(0, 0);
    STAGE(1, 1);

    #pragma unroll
    for (int t = 0; t < 16; ++t) {
        if (t < 15) { asm volatile("s_waitcnt vmcnt(3)" ::: "memory"); }
        else        { asm volatile("s_waitcnt vmcnt(0)" ::: "memory"); }
        __builtin_amdgcn_s_barrier();
        __builtin_amdgcn_sched_barrier(0);
        if (t + 2 < 16) STAGE(t + 2, (t + 2) % 3);
        const unsigned short* Ab = As3[t % 3];
        const unsigned short* Bb = Bs3[t % 3];
        bf16x8 a[4], b[4];
        #pragma unroll
        for (int mi = 0; mi < 4; ++mi)
            a[mi] = *(const bf16x8*)&Ab[(wrM * 64 + mi * 16 + l15) * 32 + ca];
        #pragma unroll
        for (int ni = 0; ni < 4; ++ni)
            b[ni] = *(const bf16x8*)&Bb[(wcN * 64 + ni * 16 + l15) * 32 + ca];
        __builtin_amdgcn_s_setprio(1);
        #pragma unroll
        for (int mi = 0; mi < 4; ++mi)
            #pragma unroll
            for (int ni = 0; ni < 4; ++ni)
                acc[mi][ni] = __builtin_amdgcn_mfma_f32_16x16x32_bf16(a[mi], b[ni], acc[mi][ni], 0, 0, 0);
        __builtin_amdgcn_s_setprio(0);
    }
#undef STAGE

    // Epilogue: per-row partial max / first-argmax / sumexp over this block's 256 cols.
    __syncthreads();
    float* redM = (float*)&As3[0][0];    // [4][128]
    float* redS = redM + 4 * 128;
    int*   redI = (int*)(redS + 4 * 128);

    #pragma unroll
    for (int mi = 0; mi < 4; ++mi) {
        #pragma unroll
        for (int r = 0; r < 4; ++r) {
            const int rl = wrM * 64 + mi * 16 + q * 4 + r;   // local row 0..127
            float lm = -INFINITY; int li = 0;
            #pragma unroll
            for (int ni = 0; ni < 4; ++ni) {
                const float v = acc[mi][ni][r];
                const int col = wcN * 64 + ni * 16 + l15;
                if (v > lm) { lm = v; li = col; }            // ascending col per lane
            }
            #pragma unroll
            for (int mk = 8; mk >= 1; mk >>= 1) {
                const float ov = __shfl_xor(lm, mk);
                const int   oi = __shfl_xor(li, mk);
                if (ov > lm || (ov == lm && oi < li)) { lm = ov; li = oi; }
            }
            float le = 0.f;
            #pragma unroll
            for (int ni = 0; ni < 4; ++ni) le += __expf(acc[mi][ni][r] - lm);
            #pragma unroll
            for (int mk = 8; mk >= 1; mk >>= 1) le += __shfl_xor(le, mk);

            if (l15 == 0) { redM[wcN * 128 + rl] = lm; redS[wcN * 128 + rl] = le; redI[wcN * 128 + rl] = li; }

            const int mg = m0 + rl;
            if (mg < MROWS) {
                const int bb = mg / 511, tt = mg - bb * 511;
                const int tv = codes[bb * NPOS + tt + 1];
                const int rel = tv - n0;
                #pragma unroll
                for (int ni = 0; ni < 4; ++ni) {
                    const int base = wcN * 64 + ni * 16;
                    if (rel >= base && rel < base + 16 && (rel - base) == l15)
                        tgtlog[mg] = acc[mi][ni][r];
                }
            }
        }
    }
    __syncthreads();
    if (tid < 128) {
        const int rl = tid;
        const int mg = m0 + rl;
        if (mg < MROWS) {
            float gm = -INFINITY; int gi = 0x7fffffff;
            #pragma unroll
            for (int g2 = 0; g2 < 4; ++g2) {
                const float mv = redM[g2 * 128 + rl];
                const int   iv = g2 * 64 + redI[g2 * 128 + rl];
                if (mv > gm || (mv == gm && iv < gi)) { gm = mv; gi = iv; }
            }
            float S = 0.f;
            #pragma unroll
            for (int g2 = 0; g2 < 4; ++g2) S += redS[g2 * 128 + rl] * __expf(redM[g2 * 128 + rl] - gm);
            pm[(size_t)vt * MPAD + mg]   = gm;
            ps[(size_t)vt * MPAD + mg]   = S;
            pidx[(size_t)vt * MPAD + mg] = n0 + gi;
        }
    }

    // ---- ticket: last block performs the global combine + reduction ----
    __syncthreads();
    if (tid == 0) {
        __threadfence();
        isLast = (atomicAdd(&sctrl[0], 1) == NBLK - 1);
    }
    __syncthreads();
    if (!isLast) return;
    __threadfence();

    float* fin0 = (float*)&Bs3[0][0];
    float* fin1 = fin0 + 512;
    float* fin2 = fin1 + 512;
    int*   fin3 = (int*)(fin2 + 512);

    float sn = 0.f, sc = 0.f, sm = 0.f; int uq = 0;
    #pragma unroll
    for (int c = 0; c < 16; ++c) {
        const int g = c * 512 + tid;
        if (g >= MROWS) continue;
        float gm = -INFINITY; int gi = 0;
        #pragma unroll 8
        for (int nt = 0; nt < NVT; ++nt) {
            const float v = pm[(size_t)nt * MPAD + g];
            if (v > gm) { gm = v; gi = pidx[(size_t)nt * MPAD + g]; }
        }
        float S = 0.f;
        #pragma unroll 8
        for (int nt = 0; nt < NVT; ++nt) S += ps[(size_t)nt * MPAD + g] * __expf(pm[(size_t)nt * MPAD + g] - gm);
        const float lse = gm + logf(S);
        const int b = g / 511, t = g - b * 511;
        const int tv = codes[b * NPOS + t + 1];
        const int L = lens[b];
        const int s = t + 1;
        const bool mf = (s < (L / 4)) && (4 * s + 3 < L);
        if (mf) {
            sn += lse - tgtlog[g];
            sc += (gi == tv) ? 1.f : 0.f;
            sm += 1.f;
            if (atomicExch(&presence[tv], 1) == 0) uq++;
        }
    }
    fin0[tid] = sn; fin1[tid] = sc; fin2[tid] = sm; fin3[tid] = uq;
    __syncthreads();
    for (int st = 256; st > 0; st >>= 1) {
        if (tid < st) { fin0[tid] += fin0[tid + st]; fin1[tid] += fin1[tid + st];
                        fin2[tid] += fin2[tid + st]; fin3[tid] += fin3[tid + st]; }
        __syncthreads();
    }
    if (tid == 0) {
        const float tm = fin2[0];
        out[0] = fin0[0] / tm;
        out[1] = fin1[0] / tm;
        out[2] = tm;
        out[3] = (float)fin3[0];
    }
}

extern "C" void kernel_launch(void* const* d_in, const int* in_sizes, int n_in,
                              void* d_out, int out_size, void* d_ws, size_t ws_size,
                              hipStream_t stream) {
    const float* feats = (const float*)d_in[0];
    const int*   lens  = (const int*)d_in[1];
    const float* enc   = (const float*)d_in[2];
    const float* proj  = (const float*)d_in[3];
    const float* emb   = (const float*)d_in[4];
    const float* tno   = (const float*)d_in[5];
    float* out = (float*)d_out;

    int* codes          = (int*)d_ws;                        // 8192
    int* presence       = codes + MPAD;                      // 8192
    int* sctrl          = presence + MPAD;                   // 64
    float* pm           = (float*)(sctrl + 64);              // 32*8192
    float* ps           = pm + (size_t)NVT * MPAD;           // 32*8192
    int* pidx           = (int*)(ps + (size_t)NVT * MPAD);   // 32*8192
    float* tgtlog       = (float*)(pidx + (size_t)NVT * MPAD); // 8192
    unsigned short* encB = (unsigned short*)(tgtlog + MPAD); // 8192*512
    unsigned short* tnoT = encB + (size_t)MPAD * ENCD;       // 8192*512

    hipLaunchKernelGGL(prep_kernel, dim3(2048), dim3(256), 0, stream,
                       feats, proj, emb, enc, tno, codes, presence, sctrl, encB, tnoT);
    hipLaunchKernelGGL(logits_mfma, dim3(NBLK), dim3(512), 0, stream,
                       encB, tnoT, codes, lens, pm, ps, pidx, tgtlog, presence, sctrl, out);
}

// Round 8
// 422.325 us; speedup vs baseline: 1.1066x; 1.1066x over previous
//
#include <hip/hip_runtime.h>
#include <math.h>

typedef __attribute__((ext_vector_type(4))) float f32x4;
typedef __attribute__((ext_vector_type(8))) short bf16x8;

// Problem constants
#define NB 16
#define NT 2048
#define NMEL 80
#define NPOS 512          // stacked positions per batch
#define EDIM 16
#define NEMB 8192
#define ENCD 512
#define MROWS (NB*511)    // 8176 logit rows
#define MPAD 8192
#define NVT 64            // 8192 / 128 col tiles

__device__ __forceinline__ unsigned short f2bf(float x) {
    union { float f; unsigned u; } v; v.f = x;
    unsigned r = v.u + 0x7fffu + ((v.u >> 16) & 1u);
    return (unsigned short)(r >> 16);
}

__device__ __forceinline__ void gl_lds16(const void* gsrc, void* lds) {
    __builtin_amdgcn_global_load_lds(
        (const __attribute__((address_space(1))) unsigned int*)gsrc,
        (__attribute__((address_space(3))) unsigned int*)lds,
        16, 0, 0);
}

// ---------------- Kernel 1: prep = codes (blocks 0..511) + enc->bf16 (512..1023)
//                  + tno->bf16 transpose (1024..2047). Also zeroes presence.
__global__ __launch_bounds__(256) void prep_kernel(
    const float* __restrict__ feats, const float* __restrict__ proj,
    const float* __restrict__ emb, const float* __restrict__ enc,
    const float* __restrict__ tno,
    int* __restrict__ codes, int* __restrict__ presence,
    unsigned short* __restrict__ encB, unsigned short* __restrict__ tnoT)
{
    __shared__ float embS[512][EDIM];       // 64B rows -> ds_read_b128 eligible
    __shared__ float e2S[512];              // 0.5*||e||^2, separate to keep rows aligned
    __shared__ float tileT[32][33];         // tno transpose staging
    const int bid = blockIdx.x;
    const int tid = threadIdx.x;

    if (bid < 512) {
        // ---- codes path ----
        const int lane = tid & 63;
        const int wave = tid >> 6;
        const int gbase = bid * 16 + wave * 4;
        if (bid < 32) presence[bid * 256 + tid] = 0;

        float yn[4][EDIM];
        #pragma unroll
        for (int pi = 0; pi < 4; ++pi) {
            const int g = gbase + pi;
            const int b = g >> 9;
            const int i = g & 511;
            float xv[5];
            float s = 0.f, sq = 0.f;
            #pragma unroll
            for (int qq = 0; qq < 5; ++qq) {
                const int d = lane + 64 * qq;
                const int j = d / 80, k = d - j * 80;
                const float v = feats[((b * NT) + (i * 4 + j)) * NMEL + k];
                xv[qq] = v; s += v; sq += v * v;
            }
            for (int m = 1; m < 64; m <<= 1) { s += __shfl_xor(s, m); sq += __shfl_xor(sq, m); }
            const float mean = s * (1.0f / 320.0f);
            const float var  = sq * (1.0f / 320.0f) - mean * mean;
            const float rstd = rsqrtf(var + 1e-6f);
            float acc[EDIM];
            #pragma unroll
            for (int e = 0; e < EDIM; ++e) acc[e] = 0.f;
            #pragma unroll
            for (int qq = 0; qq < 5; ++qq) {
                const int d = lane + 64 * qq;
                const float xn = (xv[qq] - mean) * rstd;
                #pragma unroll
                for (int e = 0; e < EDIM; ++e) acc[e] += xn * proj[d * EDIM + e];
            }
            for (int m = 1; m < 64; m <<= 1) {
                #pragma unroll
                for (int e = 0; e < EDIM; ++e) acc[e] += __shfl_xor(acc[e], m);
            }
            float nsq = 0.f;
            #pragma unroll
            for (int e = 0; e < EDIM; ++e) nsq += acc[e] * acc[e];
            const float inv = 1.0f / (sqrtf(nsq) + 1e-8f);
            #pragma unroll
            for (int e = 0; e < EDIM; ++e) yn[pi][e] = acc[e] * inv;
        }

        float mind[4]; int mini[4];
        #pragma unroll
        for (int pi = 0; pi < 4; ++pi) { mind[pi] = INFINITY; mini[pi] = 0x7fffffff; }

        for (int c = 0; c < 16; ++c) {
            __syncthreads();
            #pragma unroll
            for (int r = 0; r < 32; ++r) {
                const int flat = r * 256 + tid;
                embS[flat >> 4][flat & 15] = emb[c * 8192 + flat];
            }
            __syncthreads();
            #pragma unroll
            for (int rr = 0; rr < 2; ++rr) {
                const int vl = tid * 2 + rr;
                const float4 a0 = *(const float4*)&embS[vl][0];
                const float4 a1 = *(const float4*)&embS[vl][4];
                const float4 a2 = *(const float4*)&embS[vl][8];
                const float4 a3 = *(const float4*)&embS[vl][12];
                const float e2 = a0.x*a0.x + a0.y*a0.y + a0.z*a0.z + a0.w*a0.w
                               + a1.x*a1.x + a1.y*a1.y + a1.z*a1.z + a1.w*a1.w
                               + a2.x*a2.x + a2.y*a2.y + a2.z*a2.z + a2.w*a2.w
                               + a3.x*a3.x + a3.y*a3.y + a3.z*a3.z + a3.w*a3.w;
                e2S[vl] = 0.5f * e2;
            }
            __syncthreads();
            #pragma unroll
            for (int qq = 0; qq < 8; ++qq) {
                const int vl = lane + 64 * qq;
                const float4 e0 = *(const float4*)&embS[vl][0];
                const float4 e1 = *(const float4*)&embS[vl][4];
                const float4 e2v = *(const float4*)&embS[vl][8];
                const float4 e3 = *(const float4*)&embS[vl][12];
                const float h2 = e2S[vl];
                const int v = c * 512 + vl;
                #pragma unroll
                for (int pi = 0; pi < 4; ++pi) {
                    float dot = yn[pi][0]*e0.x + yn[pi][1]*e0.y + yn[pi][2]*e0.z + yn[pi][3]*e0.w
                              + yn[pi][4]*e1.x + yn[pi][5]*e1.y + yn[pi][6]*e1.z + yn[pi][7]*e1.w
                              + yn[pi][8]*e2v.x + yn[pi][9]*e2v.y + yn[pi][10]*e2v.z + yn[pi][11]*e2v.w
                              + yn[pi][12]*e3.x + yn[pi][13]*e3.y + yn[pi][14]*e3.z + yn[pi][15]*e3.w;
                    const float sc = h2 - dot;
                    if (sc < mind[pi]) { mind[pi] = sc; mini[pi] = v; }
                }
            }
        }
        for (int m = 1; m < 64; m <<= 1) {
            #pragma unroll
            for (int pi = 0; pi < 4; ++pi) {
                const float ov = __shfl_xor(mind[pi], m);
                const int   oi = __shfl_xor(mini[pi], m);
                if (ov < mind[pi] || (ov == mind[pi] && oi < mini[pi])) { mind[pi] = ov; mini[pi] = oi; }
            }
        }
        if (lane == 0) {
            #pragma unroll
            for (int pi = 0; pi < 4; ++pi) codes[gbase + pi] = mini[pi];
        }
    } else if (bid < 1024) {
        // ---- enc f32 -> encB bf16 [8192][512], padded rows zero ----
        const int bid2 = bid - 512;          // 0..511 -> 16 rows each
        #pragma unroll
        for (int pass = 0; pass < 4; ++pass) {
            const int m = bid2 * 16 + pass * 4 + (tid >> 6);
            const int d = (tid & 63) * 8;
            bf16x8 o;
            if (m < MROWS) {
                const int b = m / 511, t = m - b * 511;
                const float4 f0 = *(const float4*)&enc[((size_t)(b * 512 + t)) * ENCD + d];
                const float4 f1 = *(const float4*)&enc[((size_t)(b * 512 + t)) * ENCD + d + 4];
                o[0] = f2bf(f0.x); o[1] = f2bf(f0.y); o[2] = f2bf(f0.z); o[3] = f2bf(f0.w);
                o[4] = f2bf(f1.x); o[5] = f2bf(f1.y); o[6] = f2bf(f1.z); o[7] = f2bf(f1.w);
            } else {
                o = (bf16x8){0,0,0,0,0,0,0,0};
            }
            *(bf16x8*)&encB[(size_t)m * ENCD + d] = o;
        }
    } else {
        // ---- tno f32 [512][8192] -> tnoT bf16 [8192][512] ----
        const int bid2 = bid - 1024;         // 0..1023 -> 4 tiles each
        const int tx = tid & 31, ty = tid >> 5;   // 32 x 8
        #pragma unroll
        for (int it = 0; it < 4; ++it) {
            const int tile = bid2 * 4 + it;       // 0..4095
            const int n0 = (tile & 255) * 32;
            const int k0 = (tile >> 8) * 32;
            __syncthreads();
            #pragma unroll
            for (int i = 0; i < 4; ++i)
                tileT[ty + 8 * i][tx] = tno[(size_t)(k0 + ty + 8 * i) * NEMB + n0 + tx];
            __syncthreads();
            #pragma unroll
            for (int i = 0; i < 4; ++i)
                tnoT[(size_t)(n0 + ty + 8 * i) * ENCD + k0 + tx] = f2bf(tileT[tx][ty + 8 * i]);
        }
    }
}

// ---------------- Kernel 2: bf16 MFMA GEMM, BK=32, triple-buffered counted-vmcnt (r4-proven) ----
__global__ __launch_bounds__(256, 3) void logits_mfma(
    const unsigned short* __restrict__ encB, const unsigned short* __restrict__ tnoT,
    const int* __restrict__ codes,
    float* __restrict__ pm, float* __restrict__ ps, int* __restrict__ pidx,
    float* __restrict__ tgtlog)
{
    __shared__ __align__(16) unsigned short As3[3][128 * 32];
    __shared__ __align__(16) unsigned short Bs3[3][128 * 32];
    __shared__ float redM[2][128];
    __shared__ float redS[2][128];
    __shared__ int   redI[2][128];

    const int tid  = threadIdx.x;
    const int lane = tid & 63;
    const int wave = tid >> 6;
    const int wr = wave >> 1, wc = wave & 1;

    // XCD-aware mapping, mt-fastest within each XCD chunk
    const int bid = blockIdx.x;
    const int xcd = bid & 7;
    const int idx = bid >> 3;
    const int mt  = xcd * 8 + (idx & 7);
    const int vt  = idx >> 3;
    const int m0 = mt * 128, n0 = vt * 128;

    // staging lane constants: rows of 32 bf16 (64B); involution slot = chunk ^ ((r>>1)&3)
    const int rb  = lane >> 2;                               // 0..15
    const int gc8 = ((lane & 3) ^ ((lane >> 3) & 3)) * 8;    // pre-swizzled source chunk
    const size_t abase0 = (size_t)(m0 + wave * 32 + rb) * ENCD + gc8;
    const size_t bbase0 = (size_t)(n0 + wave * 32 + rb) * ENCD + gc8;

#define STAGE(t, buf)                                                                        \
    {                                                                                        \
        const int k0s = (t) * 32;                                                            \
        gl_lds16(encB + abase0 + k0s,              &As3[buf][(wave * 32) * 32]);             \
        gl_lds16(tnoT + bbase0 + k0s,              &Bs3[buf][(wave * 32) * 32]);             \
        gl_lds16(encB + abase0 + 16 * ENCD + k0s,  &As3[buf][(wave * 32 + 16) * 32]);        \
        gl_lds16(tnoT + bbase0 + 16 * ENCD + k0s,  &Bs3[buf][(wave * 32 + 16) * 32]);        \
    }

    f32x4 acc[4][4];
    #pragma unroll
    for (int i = 0; i < 4; ++i)
        #pragma unroll
        for (int j = 0; j < 4; ++j)
            acc[i][j] = (f32x4){0.f, 0.f, 0.f, 0.f};

    const int l15 = lane & 15, q = lane >> 4;
    const int ca = (q ^ ((l15 >> 1) & 3)) * 8;   // swizzled chunk offset for fragment reads

    STAGE(0, 0);
    STAGE(1, 1);

    #pragma unroll
    for (int t = 0; t < 16; ++t) {
        if (t < 15) { asm volatile("s_waitcnt vmcnt(4)" ::: "memory"); }
        else        { asm volatile("s_waitcnt vmcnt(0)" ::: "memory"); }
        __builtin_amdgcn_s_barrier();
        __builtin_amdgcn_sched_barrier(0);
        if (t + 2 < 16) {
            const int nb = (t + 2) % 3;
            STAGE(t + 2, nb);
        }
        const unsigned short* Ab = As3[t % 3];
        const unsigned short* Bb = Bs3[t % 3];
        bf16x8 a[4], b[4];
        #pragma unroll
        for (int mi = 0; mi < 4; ++mi)
            a[mi] = *(const bf16x8*)&Ab[(wr * 64 + mi * 16 + l15) * 32 + ca];
        #pragma unroll
        for (int ni = 0; ni < 4; ++ni)
            b[ni] = *(const bf16x8*)&Bb[(wc * 64 + ni * 16 + l15) * 32 + ca];
        __builtin_amdgcn_s_setprio(1);
        #pragma unroll
        for (int mi = 0; mi < 4; ++mi)
            #pragma unroll
            for (int ni = 0; ni < 4; ++ni)
                acc[mi][ni] = __builtin_amdgcn_mfma_f32_16x16x32_bf16(a[mi], b[ni], acc[mi][ni], 0, 0, 0);
        __builtin_amdgcn_s_setprio(0);
    }
#undef STAGE

    // Epilogue: per-row partial max / first-argmax / sumexp over this block's 128 cols.
    #pragma unroll
    for (int mi = 0; mi < 4; ++mi) {
        #pragma unroll
        for (int r = 0; r < 4; ++r) {
            const int rl = wr * 64 + mi * 16 + q * 4 + r;   // local row 0..127
            float lm = -INFINITY; int li = 0;
            #pragma unroll
            for (int ni = 0; ni < 4; ++ni) {
                const float v = acc[mi][ni][r];
                const int col = wc * 64 + ni * 16 + l15;
                if (v > lm) { lm = v; li = col; }           // ascending col per lane
            }
            #pragma unroll
            for (int mk = 8; mk >= 1; mk >>= 1) {
                const float ov = __shfl_xor(lm, mk);
                const int   oi = __shfl_xor(li, mk);
                if (ov > lm || (ov == lm && oi < li)) { lm = ov; li = oi; }
            }
            float le = 0.f;
            #pragma unroll
            for (int ni = 0; ni < 4; ++ni) le += __expf(acc[mi][ni][r] - lm);
            #pragma unroll
            for (int mk = 8; mk >= 1; mk >>= 1) le += __shfl_xor(le, mk);

            if (l15 == 0) { redM[wc][rl] = lm; redS[wc][rl] = le; redI[wc][rl] = li; }

            const int mg = m0 + rl;
            if (mg < MROWS) {
                const int bb = mg / 511, tt = mg - bb * 511;
                const int tv = codes[bb * NPOS + tt + 1];
                const int rel = tv - n0 - wc * 64;
                #pragma unroll
                for (int ni = 0; ni < 4; ++ni) {
                    if (rel >= ni * 16 && rel < ni * 16 + 16 && (rel & 15) == l15)
                        tgtlog[mg] = acc[mi][ni][r];
                }
            }
        }
    }
    __syncthreads();
    if (tid < 128) {
        const int rl = tid;
        const int mg = m0 + rl;
        if (mg < MROWS) {
            const float mA = redM[0][rl], mB = redM[1][rl];
            const int   iA = redI[0][rl], iB = redI[1][rl];
            float gm; int gi;
            if (mB > mA || (mB == mA && iB + 64 < iA)) { gm = mB; gi = 64 + iB; } else { gm = mA; gi = iA; }
            const float S = redS[0][rl] * __expf(mA - gm) + redS[1][rl] * __expf(mB - gm);
            pm[(size_t)vt * MPAD + mg]   = gm;
            ps[(size_t)vt * MPAD + mg]   = S;
            pidx[(size_t)vt * MPAD + mg] = n0 + gi;
        }
    }
}

// ---------------- Kernel 3: combine tile partials per row (NO atomics) ----------------
__global__ __launch_bounds__(256) void combine_kernel(
    const float* __restrict__ pm, const float* __restrict__ ps,
    const int* __restrict__ pidx, const float* __restrict__ tgtlog,
    const int* __restrict__ codes, const int* __restrict__ lens,
    float* __restrict__ rnll, float* __restrict__ rcorr, float* __restrict__ rmf,
    int* __restrict__ presence)
{
    const int g = blockIdx.x * 256 + threadIdx.x;
    if (g >= MROWS) return;
    float gm = -INFINITY; int gi = 0;
    #pragma unroll 8
    for (int nt = 0; nt < NVT; ++nt) {
        const float v = pm[(size_t)nt * MPAD + g];
        if (v > gm) { gm = v; gi = pidx[(size_t)nt * MPAD + g]; }
    }
    float S = 0.f;
    #pragma unroll 8
    for (int nt = 0; nt < NVT; ++nt) S += ps[(size_t)nt * MPAD + g] * __expf(pm[(size_t)nt * MPAD + g] - gm);
    const float lse = gm + logf(S);
    const int b = g / 511, t = g - b * 511;
    const int tv = codes[b * NPOS + t + 1];
    const float nll = lse - tgtlog[g];
    const int L = lens[b];
    const int s = t + 1;
    const bool mf = (s < (L / 4)) && (4 * s + 3 < L);
    rnll[g]  = mf ? nll : 0.f;
    rcorr[g] = (mf && gi == tv) ? 1.f : 0.f;
    rmf[g]   = mf ? 1.f : 0.f;
    if (mf) presence[tv] = 1;   // idempotent plain store; visibility via kernel boundary
}

// ---------------- Kernel 4: final reduction -> 4 scalars ----------------
__global__ __launch_bounds__(256) void finalize_kernel(
    const float* __restrict__ rnll, const float* __restrict__ rcorr,
    const float* __restrict__ rmf, const int* __restrict__ presence,
    float* __restrict__ out)
{
    __shared__ float sh0[256], sh1[256], sh2[256];
    __shared__ int shp[256];
    const int tid = threadIdx.x;
    float sn = 0.f, sc = 0.f, sm = 0.f; int pp = 0;
    for (int g = tid; g < MROWS; g += 256) { sn += rnll[g]; sc += rcorr[g]; sm += rmf[g]; }
    for (int v = tid; v < NEMB; v += 256) pp += presence[v];
    sh0[tid] = sn; sh1[tid] = sc; sh2[tid] = sm; shp[tid] = pp;
    __syncthreads();
    for (int s = 128; s > 0; s >>= 1) {
        if (tid < s) { sh0[tid] += sh0[tid + s]; sh1[tid] += sh1[tid + s]; sh2[tid] += sh2[tid + s]; shp[tid] += shp[tid + s]; }
        __syncthreads();
    }
    if (tid == 0) {
        const float Sm = sh2[0];
        out[0] = sh0[0] / Sm;
        out[1] = sh1[0] / Sm;
        out[2] = Sm;
        out[3] = (float)shp[0];
    }
}

extern "C" void kernel_launch(void* const* d_in, const int* in_sizes, int n_in,
                              void* d_out, int out_size, void* d_ws, size_t ws_size,
                              hipStream_t stream) {
    const float* feats = (const float*)d_in[0];
    const int*   lens  = (const int*)d_in[1];
    const float* enc   = (const float*)d_in[2];
    const float* proj  = (const float*)d_in[3];
    const float* emb   = (const float*)d_in[4];
    const float* tno   = (const float*)d_in[5];
    float* out = (float*)d_out;

    int* codes          = (int*)d_ws;                        // 8192
    int* presence       = codes + MPAD;                      // 8192
    float* pm           = (float*)(presence + MPAD);         // 64*8192
    float* ps           = pm + (size_t)NVT * MPAD;           // 64*8192
    int* pidx           = (int*)(ps + (size_t)NVT * MPAD);   // 64*8192
    float* tgtlog       = (float*)(pidx + (size_t)NVT * MPAD); // 8192
    float* rnll         = tgtlog + MPAD;
    float* rcorr        = rnll + MPAD;
    float* rmf          = rcorr + MPAD;
    unsigned short* encB = (unsigned short*)(rmf + MPAD);    // 8192*512
    unsigned short* tnoT = encB + (size_t)MPAD * ENCD;       // 8192*512

    hipLaunchKernelGGL(prep_kernel, dim3(2048), dim3(256), 0, stream,
                       feats, proj, emb, enc, tno, codes, presence, encB, tnoT);
    hipLaunchKernelGGL(logits_mfma, dim3(64 * 64), dim3(256), 0, stream, encB, tnoT, codes, pm, ps, pidx, tgtlog);
    hipLaunchKernelGGL(combine_kernel, dim3((MROWS + 255) / 256), dim3(256), 0, stream,
                       pm, ps, pidx, tgtlog, codes, lens, rnll, rcorr, rmf, presence);
    hipLaunchKernelGGL(finalize_kernel, dim3(1), dim3(256), 0, stream, rnll, rcorr, rmf, presence, out);
}

// Round 9
// 353.283 us; speedup vs baseline: 1.3229x; 1.1954x over previous
//
#include <hip/hip_runtime.h>
#include <math.h>

typedef __attribute__((ext_vector_type(4))) float f32x4;
typedef __attribute__((ext_vector_type(8))) short bf16x8;

// Problem constants
#define NB 16
#define NT 2048
#define NMEL 80
#define NPOS 512          // stacked positions per batch
#define EDIM 16
#define NEMB 8192
#define ENCD 512
#define MROWS (NB*511)    // 8176 logit rows
#define MPAD 8192
#define NVT 64            // 8192 / 128 col tiles
#define ESTR 20           // embS row stride in floats: 80B -> float4-aligned AND 2-way banks (free)

__device__ __forceinline__ unsigned short f2bf(float x) {
    union { float f; unsigned u; } v; v.f = x;
    unsigned r = v.u + 0x7fffu + ((v.u >> 16) & 1u);
    return (unsigned short)(r >> 16);
}

__device__ __forceinline__ void gl_lds16(const void* gsrc, void* lds) {
    __builtin_amdgcn_global_load_lds(
        (const __attribute__((address_space(1))) unsigned int*)gsrc,
        (__attribute__((address_space(3))) unsigned int*)lds,
        16, 0, 0);
}

// ---------------- Kernel 1: prep = codes (blocks 0..511) + enc->bf16 (512..1023)
//                  + tno->bf16 transpose (1024..2047). Also zeroes presence.
__global__ __launch_bounds__(256) void prep_kernel(
    const float* __restrict__ feats, const float* __restrict__ proj,
    const float* __restrict__ emb, const float* __restrict__ enc,
    const float* __restrict__ tno,
    int* __restrict__ codes, int* __restrict__ presence,
    unsigned short* __restrict__ encB, unsigned short* __restrict__ tnoT)
{
    __shared__ float embS[512][ESTR];       // cols 0..15 = e; col 16 = 0.5*||e||^2
    __shared__ float tileT[32][33];         // tno transpose staging
    const int bid = blockIdx.x;
    const int tid = threadIdx.x;

    if (bid < 512) {
        // ---- codes path ----
        const int lane = tid & 63;
        const int wave = tid >> 6;
        const int gbase = bid * 16 + wave * 4;
        if (bid < 32) presence[bid * 256 + tid] = 0;

        float yn[4][EDIM];
        #pragma unroll
        for (int pi = 0; pi < 4; ++pi) {
            const int g = gbase + pi;
            const int b = g >> 9;
            const int i = g & 511;
            float xv[5];
            float s = 0.f, sq = 0.f;
            #pragma unroll
            for (int qq = 0; qq < 5; ++qq) {
                const int d = lane + 64 * qq;
                const int j = d / 80, k = d - j * 80;
                const float v = feats[((b * NT) + (i * 4 + j)) * NMEL + k];
                xv[qq] = v; s += v; sq += v * v;
            }
            for (int m = 1; m < 64; m <<= 1) { s += __shfl_xor(s, m); sq += __shfl_xor(sq, m); }
            const float mean = s * (1.0f / 320.0f);
            const float var  = sq * (1.0f / 320.0f) - mean * mean;
            const float rstd = rsqrtf(var + 1e-6f);
            float acc[EDIM];
            #pragma unroll
            for (int e = 0; e < EDIM; ++e) acc[e] = 0.f;
            #pragma unroll
            for (int qq = 0; qq < 5; ++qq) {
                const int d = lane + 64 * qq;
                const float xn = (xv[qq] - mean) * rstd;
                #pragma unroll
                for (int e = 0; e < EDIM; ++e) acc[e] += xn * proj[d * EDIM + e];
            }
            for (int m = 1; m < 64; m <<= 1) {
                #pragma unroll
                for (int e = 0; e < EDIM; ++e) acc[e] += __shfl_xor(acc[e], m);
            }
            float nsq = 0.f;
            #pragma unroll
            for (int e = 0; e < EDIM; ++e) nsq += acc[e] * acc[e];
            const float inv = 1.0f / (sqrtf(nsq) + 1e-8f);
            #pragma unroll
            for (int e = 0; e < EDIM; ++e) yn[pi][e] = acc[e] * inv;
        }

        float mind[4]; int mini[4];
        #pragma unroll
        for (int pi = 0; pi < 4; ++pi) { mind[pi] = INFINITY; mini[pi] = 0x7fffffff; }

        for (int c = 0; c < 16; ++c) {
            __syncthreads();
            #pragma unroll
            for (int r = 0; r < 32; ++r) {
                const int flat = r * 256 + tid;
                embS[flat >> 4][flat & 15] = emb[c * 8192 + flat];
            }
            __syncthreads();
            #pragma unroll
            for (int rr = 0; rr < 2; ++rr) {
                const int vl = tid * 2 + rr;
                const float4 a0 = *(const float4*)&embS[vl][0];
                const float4 a1 = *(const float4*)&embS[vl][4];
                const float4 a2 = *(const float4*)&embS[vl][8];
                const float4 a3 = *(const float4*)&embS[vl][12];
                const float e2 = a0.x*a0.x + a0.y*a0.y + a0.z*a0.z + a0.w*a0.w
                               + a1.x*a1.x + a1.y*a1.y + a1.z*a1.z + a1.w*a1.w
                               + a2.x*a2.x + a2.y*a2.y + a2.z*a2.z + a2.w*a2.w
                               + a3.x*a3.x + a3.y*a3.y + a3.z*a3.z + a3.w*a3.w;
                embS[vl][16] = 0.5f * e2;
            }
            __syncthreads();
            #pragma unroll
            for (int qq = 0; qq < 8; ++qq) {
                const int vl = lane + 64 * qq;
                const float4 e0 = *(const float4*)&embS[vl][0];
                const float4 e1 = *(const float4*)&embS[vl][4];
                const float4 e2v = *(const float4*)&embS[vl][8];
                const float4 e3 = *(const float4*)&embS[vl][12];
                const float h2 = embS[vl][16];
                const int v = c * 512 + vl;
                #pragma unroll
                for (int pi = 0; pi < 4; ++pi) {
                    float dot = yn[pi][0]*e0.x + yn[pi][1]*e0.y + yn[pi][2]*e0.z + yn[pi][3]*e0.w
                              + yn[pi][4]*e1.x + yn[pi][5]*e1.y + yn[pi][6]*e1.z + yn[pi][7]*e1.w
                              + yn[pi][8]*e2v.x + yn[pi][9]*e2v.y + yn[pi][10]*e2v.z + yn[pi][11]*e2v.w
                              + yn[pi][12]*e3.x + yn[pi][13]*e3.y + yn[pi][14]*e3.z + yn[pi][15]*e3.w;
                    const float sc = h2 - dot;
                    if (sc < mind[pi]) { mind[pi] = sc; mini[pi] = v; }
                }
            }
        }
        for (int m = 1; m < 64; m <<= 1) {
            #pragma unroll
            for (int pi = 0; pi < 4; ++pi) {
                const float ov = __shfl_xor(mind[pi], m);
                const int   oi = __shfl_xor(mini[pi], m);
                if (ov < mind[pi] || (ov == mind[pi] && oi < mini[pi])) { mind[pi] = ov; mini[pi] = oi; }
            }
        }
        if (lane == 0) {
            #pragma unroll
            for (int pi = 0; pi < 4; ++pi) codes[gbase + pi] = mini[pi];
        }
    } else if (bid < 1024) {
        // ---- enc f32 -> encB bf16 [8192][512], padded rows zero ----
        const int bid2 = bid - 512;          // 0..511 -> 16 rows each
        #pragma unroll
        for (int pass = 0; pass < 4; ++pass) {
            const int m = bid2 * 16 + pass * 4 + (tid >> 6);
            const int d = (tid & 63) * 8;
            bf16x8 o;
            if (m < MROWS) {
                const int b = m / 511, t = m - b * 511;
                const float4 f0 = *(const float4*)&enc[((size_t)(b * 512 + t)) * ENCD + d];
                const float4 f1 = *(const float4*)&enc[((size_t)(b * 512 + t)) * ENCD + d + 4];
                o[0] = f2bf(f0.x); o[1] = f2bf(f0.y); o[2] = f2bf(f0.z); o[3] = f2bf(f0.w);
                o[4] = f2bf(f1.x); o[5] = f2bf(f1.y); o[6] = f2bf(f1.z); o[7] = f2bf(f1.w);
            } else {
                o = (bf16x8){0,0,0,0,0,0,0,0};
            }
            *(bf16x8*)&encB[(size_t)m * ENCD + d] = o;
        }
    } else {
        // ---- tno f32 [512][8192] -> tnoT bf16 [8192][512] ----
        const int bid2 = bid - 1024;         // 0..1023 -> 4 tiles each
        const int tx = tid & 31, ty = tid >> 5;   // 32 x 8
        #pragma unroll
        for (int it = 0; it < 4; ++it) {
            const int tile = bid2 * 4 + it;       // 0..4095
            const int n0 = (tile & 255) * 32;
            const int k0 = (tile >> 8) * 32;
            __syncthreads();
            #pragma unroll
            for (int i = 0; i < 4; ++i)
                tileT[ty + 8 * i][tx] = tno[(size_t)(k0 + ty + 8 * i) * NEMB + n0 + tx];
            __syncthreads();
            #pragma unroll
            for (int i = 0; i < 4; ++i)
                tnoT[(size_t)(n0 + ty + 8 * i) * ENCD + k0 + tx] = f2bf(tileT[tx][ty + 8 * i]);
        }
    }
}

// ---------------- Kernel 2: bf16 MFMA GEMM, BK=32, triple-buffered counted-vmcnt (r4-proven) ----
__global__ __launch_bounds__(256, 3) void logits_mfma(
    const unsigned short* __restrict__ encB, const unsigned short* __restrict__ tnoT,
    const int* __restrict__ codes,
    float* __restrict__ pm, float* __restrict__ ps, int* __restrict__ pidx,
    float* __restrict__ tgtlog)
{
    __shared__ __align__(16) unsigned short As3[3][128 * 32];
    __shared__ __align__(16) unsigned short Bs3[3][128 * 32];
    __shared__ float redM[2][128];
    __shared__ float redS[2][128];
    __shared__ int   redI[2][128];

    const int tid  = threadIdx.x;
    const int lane = tid & 63;
    const int wave = tid >> 6;
    const int wr = wave >> 1, wc = wave & 1;

    // XCD-aware mapping, mt-fastest within each XCD chunk
    const int bid = blockIdx.x;
    const int xcd = bid & 7;
    const int idx = bid >> 3;
    const int mt  = xcd * 8 + (idx & 7);
    const int vt  = idx >> 3;
    const int m0 = mt * 128, n0 = vt * 128;

    // staging lane constants: rows of 32 bf16 (64B); involution slot = chunk ^ ((r>>1)&3)
    const int rb  = lane >> 2;                               // 0..15
    const int gc8 = ((lane & 3) ^ ((lane >> 3) & 3)) * 8;    // pre-swizzled source chunk
    const size_t abase0 = (size_t)(m0 + wave * 32 + rb) * ENCD + gc8;
    const size_t bbase0 = (size_t)(n0 + wave * 32 + rb) * ENCD + gc8;

#define STAGE(t, buf)                                                                        \
    {                                                                                        \
        const int k0s = (t) * 32;                                                            \
        gl_lds16(encB + abase0 + k0s,              &As3[buf][(wave * 32) * 32]);             \
        gl_lds16(tnoT + bbase0 + k0s,              &Bs3[buf][(wave * 32) * 32]);             \
        gl_lds16(encB + abase0 + 16 * ENCD + k0s,  &As3[buf][(wave * 32 + 16) * 32]);        \
        gl_lds16(tnoT + bbase0 + 16 * ENCD + k0s,  &Bs3[buf][(wave * 32 + 16) * 32]);        \
    }

    f32x4 acc[4][4];
    #pragma unroll
    for (int i = 0; i < 4; ++i)
        #pragma unroll
        for (int j = 0; j < 4; ++j)
            acc[i][j] = (f32x4){0.f, 0.f, 0.f, 0.f};

    const int l15 = lane & 15, q = lane >> 4;
    const int ca = (q ^ ((l15 >> 1) & 3)) * 8;   // swizzled chunk offset for fragment reads

    STAGE(0, 0);
    STAGE(1, 1);

    #pragma unroll
    for (int t = 0; t < 16; ++t) {
        if (t < 15) { asm volatile("s_waitcnt vmcnt(4)" ::: "memory"); }
        else        { asm volatile("s_waitcnt vmcnt(0)" ::: "memory"); }
        __builtin_amdgcn_s_barrier();
        __builtin_amdgcn_sched_barrier(0);
        if (t + 2 < 16) {
            const int nb = (t + 2) % 3;
            STAGE(t + 2, nb);
        }
        const unsigned short* Ab = As3[t % 3];
        const unsigned short* Bb = Bs3[t % 3];
        bf16x8 a[4], b[4];
        #pragma unroll
        for (int mi = 0; mi < 4; ++mi)
            a[mi] = *(const bf16x8*)&Ab[(wr * 64 + mi * 16 + l15) * 32 + ca];
        #pragma unroll
        for (int ni = 0; ni < 4; ++ni)
            b[ni] = *(const bf16x8*)&Bb[(wc * 64 + ni * 16 + l15) * 32 + ca];
        __builtin_amdgcn_s_setprio(1);
        #pragma unroll
        for (int mi = 0; mi < 4; ++mi)
            #pragma unroll
            for (int ni = 0; ni < 4; ++ni)
                acc[mi][ni] = __builtin_amdgcn_mfma_f32_16x16x32_bf16(a[mi], b[ni], acc[mi][ni], 0, 0, 0);
        __builtin_amdgcn_s_setprio(0);
    }
#undef STAGE

    // Epilogue: per-row partial max / first-argmax / sumexp over this block's 128 cols.
    #pragma unroll
    for (int mi = 0; mi < 4; ++mi) {
        #pragma unroll
        for (int r = 0; r < 4; ++r) {
            const int rl = wr * 64 + mi * 16 + q * 4 + r;   // local row 0..127
            float lm = -INFINITY; int li = 0;
            #pragma unroll
            for (int ni = 0; ni < 4; ++ni) {
                const float v = acc[mi][ni][r];
                const int col = wc * 64 + ni * 16 + l15;
                if (v > lm) { lm = v; li = col; }           // ascending col per lane
            }
            #pragma unroll
            for (int mk = 8; mk >= 1; mk >>= 1) {
                const float ov = __shfl_xor(lm, mk);
                const int   oi = __shfl_xor(li, mk);
                if (ov > lm || (ov == lm && oi < li)) { lm = ov; li = oi; }
            }
            float le = 0.f;
            #pragma unroll
            for (int ni = 0; ni < 4; ++ni) le += __expf(acc[mi][ni][r] - lm);
            #pragma unroll
            for (int mk = 8; mk >= 1; mk >>= 1) le += __shfl_xor(le, mk);

            if (l15 == 0) { redM[wc][rl] = lm; redS[wc][rl] = le; redI[wc][rl] = li; }

            const int mg = m0 + rl;
            if (mg < MROWS) {
                const int bb = mg / 511, tt = mg - bb * 511;
                const int tv = codes[bb * NPOS + tt + 1];
                const int rel = tv - n0 - wc * 64;
                #pragma unroll
                for (int ni = 0; ni < 4; ++ni) {
                    if (rel >= ni * 16 && rel < ni * 16 + 16 && (rel & 15) == l15)
                        tgtlog[mg] = acc[mi][ni][r];
                }
            }
        }
    }
    __syncthreads();
    if (tid < 128) {
        const int rl = tid;
        const int mg = m0 + rl;
        if (mg < MROWS) {
            const float mA = redM[0][rl], mB = redM[1][rl];
            const int   iA = redI[0][rl], iB = redI[1][rl];
            float gm; int gi;
            if (mB > mA || (mB == mA && iB + 64 < iA)) { gm = mB; gi = 64 + iB; } else { gm = mA; gi = iA; }
            const float S = redS[0][rl] * __expf(mA - gm) + redS[1][rl] * __expf(mB - gm);
            pm[(size_t)vt * MPAD + mg]   = gm;
            ps[(size_t)vt * MPAD + mg]   = S;
            pidx[(size_t)vt * MPAD + mg] = n0 + gi;
        }
    }
}

// ---------------- Kernel 3: combine tile partials per row (NO atomics) ----------------
__global__ __launch_bounds__(256) void combine_kernel(
    const float* __restrict__ pm, const float* __restrict__ ps,
    const int* __restrict__ pidx, const float* __restrict__ tgtlog,
    const int* __restrict__ codes, const int* __restrict__ lens,
    float* __restrict__ rnll, float* __restrict__ rcorr, float* __restrict__ rmf,
    int* __restrict__ presence)
{
    const int g = blockIdx.x * 256 + threadIdx.x;
    if (g >= MROWS) return;
    float gm = -INFINITY; int gi = 0;
    #pragma unroll 8
    for (int nt = 0; nt < NVT; ++nt) {
        const float v = pm[(size_t)nt * MPAD + g];
        if (v > gm) { gm = v; gi = pidx[(size_t)nt * MPAD + g]; }
    }
    float S = 0.f;
    #pragma unroll 8
    for (int nt = 0; nt < NVT; ++nt) S += ps[(size_t)nt * MPAD + g] * __expf(pm[(size_t)nt * MPAD + g] - gm);
    const float lse = gm + logf(S);
    const int b = g / 511, t = g - b * 511;
    const int tv = codes[b * NPOS + t + 1];
    const float nll = lse - tgtlog[g];
    const int L = lens[b];
    const int s = t + 1;
    const bool mf = (s < (L / 4)) && (4 * s + 3 < L);
    rnll[g]  = mf ? nll : 0.f;
    rcorr[g] = (mf && gi == tv) ? 1.f : 0.f;
    rmf[g]   = mf ? 1.f : 0.f;
    if (mf) presence[tv] = 1;   // idempotent plain store; visibility via kernel boundary
}

// ---------------- Kernel 4: final reduction -> 4 scalars ----------------
__global__ __launch_bounds__(256) void finalize_kernel(
    const float* __restrict__ rnll, const float* __restrict__ rcorr,
    const float* __restrict__ rmf, const int* __restrict__ presence,
    float* __restrict__ out)
{
    __shared__ float sh0[256], sh1[256], sh2[256];
    __shared__ int shp[256];
    const int tid = threadIdx.x;
    float sn = 0.f, sc = 0.f, sm = 0.f; int pp = 0;
    for (int g = tid; g < MROWS; g += 256) { sn += rnll[g]; sc += rcorr[g]; sm += rmf[g]; }
    for (int v = tid; v < NEMB; v += 256) pp += presence[v];
    sh0[tid] = sn; sh1[tid] = sc; sh2[tid] = sm; shp[tid] = pp;
    __syncthreads();
    for (int s = 128; s > 0; s >>= 1) {
        if (tid < s) { sh0[tid] += sh0[tid + s]; sh1[tid] += sh1[tid + s]; sh2[tid] += sh2[tid + s]; shp[tid] += shp[tid + s]; }
        __syncthreads();
    }
    if (tid == 0) {
        const float Sm = sh2[0];
        out[0] = sh0[0] / Sm;
        out[1] = sh1[0] / Sm;
        out[2] = Sm;
        out[3] = (float)shp[0];
    }
}

extern "C" void kernel_launch(void* const* d_in, const int* in_sizes, int n_in,
                              void* d_out, int out_size, void* d_ws, size_t ws_size,
                              hipStream_t stream) {
    const float* feats = (const float*)d_in[0];
    const int*   lens  = (const int*)d_in[1];
    const float* enc   = (const float*)d_in[2];
    const float* proj  = (const float*)d_in[3];
    const float* emb   = (const float*)d_in[4];
    const float* tno   = (const float*)d_in[5];
    float* out = (float*)d_out;

    int* codes          = (int*)d_ws;                        // 8192
    int* presence       = codes + MPAD;                      // 8192
    float* pm           = (float*)(presence + MPAD);         // 64*8192
    float* ps           = pm + (size_t)NVT * MPAD;           // 64*8192
    int* pidx           = (int*)(ps + (size_t)NVT * MPAD);   // 64*8192
    float* tgtlog       = (float*)(pidx + (size_t)NVT * MPAD); // 8192
    float* rnll         = tgtlog + MPAD;
    float* rcorr        = rnll + MPAD;
    float* rmf          = rcorr + MPAD;
    unsigned short* encB = (unsigned short*)(rmf + MPAD);    // 8192*512
    unsigned short* tnoT = encB + (size_t)MPAD * ENCD;       // 8192*512

    hipLaunchKernelGGL(prep_kernel, dim3(2048), dim3(256), 0, stream,
                       feats, proj, emb, enc, tno, codes, presence, encB, tnoT);
    hipLaunchKernelGGL(logits_mfma, dim3(64 * 64), dim3(256), 0, stream, encB, tnoT, codes, pm, ps, pidx, tgtlog);
    hipLaunchKernelGGL(combine_kernel, dim3((MROWS + 255) / 256), dim3(256), 0, stream,
                       pm, ps, pidx, tgtlog, codes, lens, rnll, rcorr, rmf, presence);
    hipLaunchKernelGGL(finalize_kernel, dim3(1), dim3(256), 0, stream, rnll, rcorr, rmf, presence, out);
}

// Round 10
// 271.761 us; speedup vs baseline: 1.7197x; 1.3000x over previous
//
#include <hip/hip_runtime.h>
#include <math.h>

typedef __attribute__((ext_vector_type(4))) float f32x4;
typedef __attribute__((ext_vector_type(8))) short bf16x8;

// Problem constants
#define NB 16
#define NT 2048
#define NMEL 80
#define NPOS 512          // stacked positions per batch
#define EDIM 16
#define NEMB 8192
#define ENCD 512
#define MROWS (NB*511)    // 8176 logit rows
#define MPAD 8192
#define NVT 64            // 8192 / 128 col tiles

__device__ __forceinline__ unsigned short f2bf(float x) {
    union { float f; unsigned u; } v; v.f = x;
    unsigned r = v.u + 0x7fffu + ((v.u >> 16) & 1u);
    return (unsigned short)(r >> 16);
}

__device__ __forceinline__ void gl_lds16(const void* gsrc, void* lds) {
    __builtin_amdgcn_global_load_lds(
        (const __attribute__((address_space(1))) unsigned int*)gsrc,
        (__attribute__((address_space(3))) unsigned int*)lds,
        16, 0, 0);
}

// ---------------- Kernel 1: prep = codes (blocks 0..511, r6-proven scalar form)
//                  + enc->bf16 (512..1023) + tno->bf16 transpose (1024..2047).
__global__ __launch_bounds__(256) void prep_kernel(
    const float* __restrict__ feats, const float* __restrict__ proj,
    const float* __restrict__ emb, const float* __restrict__ enc,
    const float* __restrict__ tno,
    int* __restrict__ codes, int* __restrict__ presence,
    unsigned short* __restrict__ encB, unsigned short* __restrict__ tnoT)
{
    __shared__ float embS[512][EDIM + 1];   // col 16 = 0.5*||e||^2 ; 68B rows (scalar-friendly)
    __shared__ float tileT[32][33];         // tno transpose staging
    const int bid = blockIdx.x;
    const int tid = threadIdx.x;

    if (bid < 512) {
        // ---- codes path (r6/r7 measured ~75us) ----
        const int lane = tid & 63;
        const int wave = tid >> 6;
        const int gbase = bid * 16 + wave * 4;
        if (bid < 32) presence[bid * 256 + tid] = 0;

        float yn[4][EDIM];
        #pragma unroll
        for (int pi = 0; pi < 4; ++pi) {
            const int g = gbase + pi;
            const int b = g >> 9;
            const int i = g & 511;
            float xv[5];
            float s = 0.f, sq = 0.f;
            #pragma unroll
            for (int qq = 0; qq < 5; ++qq) {
                const int d = lane + 64 * qq;
                const int j = d / 80, k = d - j * 80;
                const float v = feats[((b * NT) + (i * 4 + j)) * NMEL + k];
                xv[qq] = v; s += v; sq += v * v;
            }
            for (int m = 1; m < 64; m <<= 1) { s += __shfl_xor(s, m); sq += __shfl_xor(sq, m); }
            const float mean = s * (1.0f / 320.0f);
            const float var  = sq * (1.0f / 320.0f) - mean * mean;
            const float rstd = rsqrtf(var + 1e-6f);
            float acc[EDIM];
            #pragma unroll
            for (int e = 0; e < EDIM; ++e) acc[e] = 0.f;
            #pragma unroll
            for (int qq = 0; qq < 5; ++qq) {
                const int d = lane + 64 * qq;
                const float xn = (xv[qq] - mean) * rstd;
                #pragma unroll
                for (int e = 0; e < EDIM; ++e) acc[e] += xn * proj[d * EDIM + e];
            }
            for (int m = 1; m < 64; m <<= 1) {
                #pragma unroll
                for (int e = 0; e < EDIM; ++e) acc[e] += __shfl_xor(acc[e], m);
            }
            float nsq = 0.f;
            #pragma unroll
            for (int e = 0; e < EDIM; ++e) nsq += acc[e] * acc[e];
            const float inv = 1.0f / (sqrtf(nsq) + 1e-8f);
            #pragma unroll
            for (int e = 0; e < EDIM; ++e) yn[pi][e] = acc[e] * inv;
        }

        float mind[4]; int mini[4];
        #pragma unroll
        for (int pi = 0; pi < 4; ++pi) { mind[pi] = INFINITY; mini[pi] = 0x7fffffff; }

        for (int c = 0; c < 16; ++c) {
            __syncthreads();
            #pragma unroll
            for (int r = 0; r < 32; ++r) {
                const int flat = r * 256 + tid;
                embS[flat >> 4][flat & 15] = emb[c * 8192 + flat];
            }
            __syncthreads();
            #pragma unroll
            for (int rr = 0; rr < 2; ++rr) {
                const int vl = tid * 2 + rr;
                float e2 = 0.f;
                #pragma unroll
                for (int e = 0; e < EDIM; ++e) e2 += embS[vl][e] * embS[vl][e];
                embS[vl][EDIM] = 0.5f * e2;
            }
            __syncthreads();
            #pragma unroll
            for (int qq = 0; qq < 8; ++qq) {
                const int vl = lane + 64 * qq;
                float ev[EDIM];
                #pragma unroll
                for (int e = 0; e < EDIM; ++e) ev[e] = embS[vl][e];
                const float h2 = embS[vl][EDIM];
                const int v = c * 512 + vl;
                #pragma unroll
                for (int pi = 0; pi < 4; ++pi) {
                    float dot = 0.f;
                    #pragma unroll
                    for (int e = 0; e < EDIM; ++e) dot += yn[pi][e] * ev[e];
                    const float sc = h2 - dot;
                    if (sc < mind[pi]) { mind[pi] = sc; mini[pi] = v; }
                }
            }
        }
        for (int m = 1; m < 64; m <<= 1) {
            #pragma unroll
            for (int pi = 0; pi < 4; ++pi) {
                const float ov = __shfl_xor(mind[pi], m);
                const int   oi = __shfl_xor(mini[pi], m);
                if (ov < mind[pi] || (ov == mind[pi] && oi < mini[pi])) { mind[pi] = ov; mini[pi] = oi; }
            }
        }
        if (lane == 0) {
            #pragma unroll
            for (int pi = 0; pi < 4; ++pi) codes[gbase + pi] = mini[pi];
        }
    } else if (bid < 1024) {
        // ---- enc f32 -> encB bf16 [8192][512], padded rows zero ----
        const int bid2 = bid - 512;          // 0..511 -> 16 rows each
        #pragma unroll
        for (int pass = 0; pass < 4; ++pass) {
            const int m = bid2 * 16 + pass * 4 + (tid >> 6);
            const int d = (tid & 63) * 8;
            bf16x8 o;
            if (m < MROWS) {
                const int b = m / 511, t = m - b * 511;
                const float4 f0 = *(const float4*)&enc[((size_t)(b * 512 + t)) * ENCD + d];
                const float4 f1 = *(const float4*)&enc[((size_t)(b * 512 + t)) * ENCD + d + 4];
                o[0] = f2bf(f0.x); o[1] = f2bf(f0.y); o[2] = f2bf(f0.z); o[3] = f2bf(f0.w);
                o[4] = f2bf(f1.x); o[5] = f2bf(f1.y); o[6] = f2bf(f1.z); o[7] = f2bf(f1.w);
            } else {
                o = (bf16x8){0,0,0,0,0,0,0,0};
            }
            *(bf16x8*)&encB[(size_t)m * ENCD + d] = o;
        }
    } else {
        // ---- tno f32 [512][8192] -> tnoT bf16 [8192][512] ----
        const int bid2 = bid - 1024;         // 0..1023 -> 4 tiles each
        const int tx = tid & 31, ty = tid >> 5;   // 32 x 8
        #pragma unroll
        for (int it = 0; it < 4; ++it) {
            const int tile = bid2 * 4 + it;       // 0..4095
            const int n0 = (tile & 255) * 32;
            const int k0 = (tile >> 8) * 32;
            __syncthreads();
            #pragma unroll
            for (int i = 0; i < 4; ++i)
                tileT[ty + 8 * i][tx] = tno[(size_t)(k0 + ty + 8 * i) * NEMB + n0 + tx];
            __syncthreads();
            #pragma unroll
            for (int i = 0; i < 4; ++i)
                tnoT[(size_t)(n0 + ty + 8 * i) * ENCD + k0 + tx] = f2bf(tileT[tx][ty + 8 * i]);
        }
    }
}

// ---------------- Kernel 2: bf16 MFMA GEMM, BK=32, triple-buffered counted-vmcnt (r4-proven) ----
__global__ __launch_bounds__(256, 3) void logits_mfma(
    const unsigned short* __restrict__ encB, const unsigned short* __restrict__ tnoT,
    const int* __restrict__ codes,
    float* __restrict__ pm, float* __restrict__ ps, int* __restrict__ pidx,
    float* __restrict__ tgtlog)
{
    __shared__ __align__(16) unsigned short As3[3][128 * 32];
    __shared__ __align__(16) unsigned short Bs3[3][128 * 32];
    __shared__ float redM[2][128];
    __shared__ float redS[2][128];
    __shared__ int   redI[2][128];

    const int tid  = threadIdx.x;
    const int lane = tid & 63;
    const int wave = tid >> 6;
    const int wr = wave >> 1, wc = wave & 1;

    // XCD-aware mapping, mt-fastest within each XCD chunk
    const int bid = blockIdx.x;
    const int xcd = bid & 7;
    const int idx = bid >> 3;
    const int mt  = xcd * 8 + (idx & 7);
    const int vt  = idx >> 3;
    const int m0 = mt * 128, n0 = vt * 128;

    // staging lane constants: rows of 32 bf16 (64B); involution slot = chunk ^ ((r>>1)&3)
    const int rb  = lane >> 2;                               // 0..15
    const int gc8 = ((lane & 3) ^ ((lane >> 3) & 3)) * 8;    // pre-swizzled source chunk
    const size_t abase0 = (size_t)(m0 + wave * 32 + rb) * ENCD + gc8;
    const size_t bbase0 = (size_t)(n0 + wave * 32 + rb) * ENCD + gc8;

#define STAGE(t, buf)                                                                        \
    {                                                                                        \
        const int k0s = (t) * 32;                                                            \
        gl_lds16(encB + abase0 + k0s,              &As3[buf][(wave * 32) * 32]);             \
        gl_lds16(tnoT + bbase0 + k0s,              &Bs3[buf][(wave * 32) * 32]);             \
        gl_lds16(encB + abase0 + 16 * ENCD + k0s,  &As3[buf][(wave * 32 + 16) * 32]);        \
        gl_lds16(tnoT + bbase0 + 16 * ENCD + k0s,  &Bs3[buf][(wave * 32 + 16) * 32]);        \
    }

    f32x4 acc[4][4];
    #pragma unroll
    for (int i = 0; i < 4; ++i)
        #pragma unroll
        for (int j = 0; j < 4; ++j)
            acc[i][j] = (f32x4){0.f, 0.f, 0.f, 0.f};

    const int l15 = lane & 15, q = lane >> 4;
    const int ca = (q ^ ((l15 >> 1) & 3)) * 8;   // swizzled chunk offset for fragment reads

    STAGE(0, 0);
    STAGE(1, 1);

    #pragma unroll
    for (int t = 0; t < 16; ++t) {
        if (t < 15) { asm volatile("s_waitcnt vmcnt(4)" ::: "memory"); }
        else        { asm volatile("s_waitcnt vmcnt(0)" ::: "memory"); }
        __builtin_amdgcn_s_barrier();
        __builtin_amdgcn_sched_barrier(0);
        if (t + 2 < 16) {
            const int nb = (t + 2) % 3;
            STAGE(t + 2, nb);
        }
        const unsigned short* Ab = As3[t % 3];
        const unsigned short* Bb = Bs3[t % 3];
        bf16x8 a[4], b[4];
        #pragma unroll
        for (int mi = 0; mi < 4; ++mi)
            a[mi] = *(const bf16x8*)&Ab[(wr * 64 + mi * 16 + l15) * 32 + ca];
        #pragma unroll
        for (int ni = 0; ni < 4; ++ni)
            b[ni] = *(const bf16x8*)&Bb[(wc * 64 + ni * 16 + l15) * 32 + ca];
        __builtin_amdgcn_s_setprio(1);
        #pragma unroll
        for (int mi = 0; mi < 4; ++mi)
            #pragma unroll
            for (int ni = 0; ni < 4; ++ni)
                acc[mi][ni] = __builtin_amdgcn_mfma_f32_16x16x32_bf16(a[mi], b[ni], acc[mi][ni], 0, 0, 0);
        __builtin_amdgcn_s_setprio(0);
    }
#undef STAGE

    // Epilogue: per-row partial max / first-argmax / sumexp over this block's 128 cols.
    #pragma unroll
    for (int mi = 0; mi < 4; ++mi) {
        #pragma unroll
        for (int r = 0; r < 4; ++r) {
            const int rl = wr * 64 + mi * 16 + q * 4 + r;   // local row 0..127
            float lm = -INFINITY; int li = 0;
            #pragma unroll
            for (int ni = 0; ni < 4; ++ni) {
                const float v = acc[mi][ni][r];
                const int col = wc * 64 + ni * 16 + l15;
                if (v > lm) { lm = v; li = col; }           // ascending col per lane
            }
            #pragma unroll
            for (int mk = 8; mk >= 1; mk >>= 1) {
                const float ov = __shfl_xor(lm, mk);
                const int   oi = __shfl_xor(li, mk);
                if (ov > lm || (ov == lm && oi < li)) { lm = ov; li = oi; }
            }
            float le = 0.f;
            #pragma unroll
            for (int ni = 0; ni < 4; ++ni) le += __expf(acc[mi][ni][r] - lm);
            #pragma unroll
            for (int mk = 8; mk >= 1; mk >>= 1) le += __shfl_xor(le, mk);

            if (l15 == 0) { redM[wc][rl] = lm; redS[wc][rl] = le; redI[wc][rl] = li; }

            const int mg = m0 + rl;
            if (mg < MROWS) {
                const int bb = mg / 511, tt = mg - bb * 511;
                const int tv = codes[bb * NPOS + tt + 1];
                const int rel = tv - n0 - wc * 64;
                #pragma unroll
                for (int ni = 0; ni < 4; ++ni) {
                    if (rel >= ni * 16 && rel < ni * 16 + 16 && (rel & 15) == l15)
                        tgtlog[mg] = acc[mi][ni][r];
                }
            }
        }
    }
    __syncthreads();
    if (tid < 128) {
        const int rl = tid;
        const int mg = m0 + rl;
        if (mg < MROWS) {
            const float mA = redM[0][rl], mB = redM[1][rl];
            const int   iA = redI[0][rl], iB = redI[1][rl];
            float gm; int gi;
            if (mB > mA || (mB == mA && iB + 64 < iA)) { gm = mB; gi = 64 + iB; } else { gm = mA; gi = iA; }
            const float S = redS[0][rl] * __expf(mA - gm) + redS[1][rl] * __expf(mB - gm);
            pm[(size_t)vt * MPAD + mg]   = gm;
            ps[(size_t)vt * MPAD + mg]   = S;
            pidx[(size_t)vt * MPAD + mg] = n0 + gi;
        }
    }
}

// ---------------- Kernel 3: combine tile partials per row (NO atomics) ----------------
__global__ __launch_bounds__(256) void combine_kernel(
    const float* __restrict__ pm, const float* __restrict__ ps,
    const int* __restrict__ pidx, const float* __restrict__ tgtlog,
    const int* __restrict__ codes, const int* __restrict__ lens,
    float* __restrict__ rnll, float* __restrict__ rcorr, float* __restrict__ rmf,
    int* __restrict__ presence)
{
    const int g = blockIdx.x * 256 + threadIdx.x;
    if (g >= MROWS) return;
    float gm = -INFINITY; int gi = 0;
    #pragma unroll 8
    for (int nt = 0; nt < NVT; ++nt) {
        const float v = pm[(size_t)nt * MPAD + g];
        if (v > gm) { gm = v; gi = pidx[(size_t)nt * MPAD + g]; }
    }
    float S = 0.f;
    #pragma unroll 8
    for (int nt = 0; nt < NVT; ++nt) S += ps[(size_t)nt * MPAD + g] * __expf(pm[(size_t)nt * MPAD + g] - gm);
    const float lse = gm + logf(S);
    const int b = g / 511, t = g - b * 511;
    const int tv = codes[b * NPOS + t + 1];
    const float nll = lse - tgtlog[g];
    const int L = lens[b];
    const int s = t + 1;
    const bool mf = (s < (L / 4)) && (4 * s + 3 < L);
    rnll[g]  = mf ? nll : 0.f;
    rcorr[g] = (mf && gi == tv) ? 1.f : 0.f;
    rmf[g]   = mf ? 1.f : 0.f;
    if (mf) presence[tv] = 1;   // idempotent plain store; visibility via kernel boundary
}

// ---------------- Kernel 4: final reduction -> 4 scalars ----------------
__global__ __launch_bounds__(256) void finalize_kernel(
    const float* __restrict__ rnll, const float* __restrict__ rcorr,
    const float* __restrict__ rmf, const int* __restrict__ presence,
    float* __restrict__ out)
{
    __shared__ float sh0[256], sh1[256], sh2[256];
    __shared__ int shp[256];
    const int tid = threadIdx.x;
    float sn = 0.f, sc = 0.f, sm = 0.f; int pp = 0;
    for (int g = tid; g < MROWS; g += 256) { sn += rnll[g]; sc += rcorr[g]; sm += rmf[g]; }
    for (int v = tid; v < NEMB; v += 256) pp += presence[v];
    sh0[tid] = sn; sh1[tid] = sc; sh2[tid] = sm; shp[tid] = pp;
    __syncthreads();
    for (int s = 128; s > 0; s >>= 1) {
        if (tid < s) { sh0[tid] += sh0[tid + s]; sh1[tid] += sh1[tid + s]; sh2[tid] += sh2[tid + s]; shp[tid] += shp[tid + s]; }
        __syncthreads();
    }
    if (tid == 0) {
        const float Sm = sh2[0];
        out[0] = sh0[0] / Sm;
        out[1] = sh1[0] / Sm;
        out[2] = Sm;
        out[3] = (float)shp[0];
    }
}

extern "C" void kernel_launch(void* const* d_in, const int* in_sizes, int n_in,
                              void* d_out, int out_size, void* d_ws, size_t ws_size,
                              hipStream_t stream) {
    const float* feats = (const float*)d_in[0];
    const int*   lens  = (const int*)d_in[1];
    const float* enc   = (const float*)d_in[2];
    const float* proj  = (const float*)d_in[3];
    const float* emb   = (const float*)d_in[4];
    const float* tno   = (const float*)d_in[5];
    float* out = (float*)d_out;

    int* codes          = (int*)d_ws;                        // 8192
    int* presence       = codes + MPAD;                      // 8192
    float* pm           = (float*)(presence + MPAD);         // 64*8192
    float* ps           = pm + (size_t)NVT * MPAD;           // 64*8192
    int* pidx           = (int*)(ps + (size_t)NVT * MPAD);   // 64*8192
    float* tgtlog       = (float*)(pidx + (size_t)NVT * MPAD); // 8192
    float* rnll         = tgtlog + MPAD;
    float* rcorr        = rnll + MPAD;
    float* rmf          = rcorr + MPAD;
    unsigned short* encB = (unsigned short*)(rmf + MPAD);    // 8192*512
    unsigned short* tnoT = encB + (size_t)MPAD * ENCD;       // 8192*512

    hipLaunchKernelGGL(prep_kernel, dim3(2048), dim3(256), 0, stream,
                       feats, proj, emb, enc, tno, codes, presence, encB, tnoT);
    hipLaunchKernelGGL(logits_mfma, dim3(64 * 64), dim3(256), 0, stream, encB, tnoT, codes, pm, ps, pidx, tgtlog);
    hipLaunchKernelGGL(combine_kernel, dim3((MROWS + 255) / 256), dim3(256), 0, stream,
                       pm, ps, pidx, tgtlog, codes, lens, rnll, rcorr, rmf, presence);
    hipLaunchKernelGGL(finalize_kernel, dim3(1), dim3(256), 0, stream, rnll, rcorr, rmf, presence, out);
}